// Round 17
// baseline (196.369 us; speedup 1.0000x reference)
//
#include <hip/hip_runtime.h>

#define DD 128

typedef short bf16x8 __attribute__((ext_vector_type(8)));
typedef float f32x4 __attribute__((ext_vector_type(4)));

__device__ __forceinline__ unsigned short f2bf(float f) {   // fp32 -> bf16, RNE
    unsigned int u = __builtin_bit_cast(unsigned int, f);
    u += 0x7fffu + ((u >> 16) & 1u);
    return (unsigned short)(u >> 16);
}
__device__ __forceinline__ float bflo(unsigned int u) { return __builtin_bit_cast(float, u << 16); }
__device__ __forceinline__ float bfhi(unsigned int u) { return __builtin_bit_cast(float, u & 0xffff0000u); }

// ---------------- scan (single kernel): per-block direct prefix + local scan ----------------
// base of block bid = sum(cnt[0..bid*256)) computed by direct strided read (L2-resident).
__global__ __launch_bounds__(256) void k_apply(const int* __restrict__ cnt,
                                               int* __restrict__ rowptr,
                                               float* __restrict__ dis, int n) {
    __shared__ int s[256];
    __shared__ int sbase;
    int t = threadIdx.x;
    int bid = blockIdx.x;
    int lim = bid * 256;

    int a = 0;
    for (int j = t; j < lim; j += 256) a += cnt[j];   // coalesced strided sum
    s[t] = a;
    __syncthreads();
    for (int off = 128; off > 0; off >>= 1) {
        if (t < off) s[t] += s[t + off];
        __syncthreads();
    }
    if (t == 0) sbase = s[0];
    __syncthreads();

    int i = lim + t;
    int c = (i < n) ? cnt[i] : 0;
    s[t] = c;
    __syncthreads();
    for (int off = 1; off < 256; off <<= 1) {
        int u = (t >= off) ? s[t - off] : 0;
        __syncthreads();
        s[t] += u;
        __syncthreads();
    }
    int base = sbase + s[t] - c;
    if (i < n) {
        rowptr[i] = base;
        dis[i] = rsqrtf((float)c + 1.0f);
        if (i == n - 1) rowptr[n] = base + c;
    }
}

// ---------------- permute: atomic-free (rank precomputed in count phase) ----------------
__global__ void k_permute(const int* __restrict__ row, const int* __restrict__ col,
                          const int* __restrict__ rowptr, const int* __restrict__ rank,
                          int* __restrict__ srow, int E) {
    int e = blockIdx.x * blockDim.x + threadIdx.x;
    if (e >= E) return;
    int p = rowptr[col[e]] + rank[e];
    srow[p] = row[e];
}

// ---------------- MFMA GEMM1: xw(bf16) = X(fp32) @ W1^T  (+ fused edge count + rank) ----------------
__global__ __launch_bounds__(512) void k_gemm_mfma(const float* __restrict__ Xv,
                                                   const float* __restrict__ W,
                                                   unsigned short* __restrict__ Y,
                                                   int nrows, int gemm_blocks,
                                                   const int* __restrict__ ecol,
                                                   int* __restrict__ cnt,
                                                   int* __restrict__ rank, int E) {
    __shared__ unsigned short Ws[128 * 128];   // 32 KB, 16B-chunk XOR swizzle
    const int t = threadIdx.x;

    if ((int)blockIdx.x >= gemm_blocks) {      // fused edge-count histogram + rank capture
        int e = (blockIdx.x - gemm_blocks) * 512 + t;
        if (e < E) {
            int r = atomicAdd(&cnt[ecol[e]], 1);
            rank[e] = r;                       // coalesced write
        }
        return;
    }

    #pragma unroll
    for (int i = 0; i < 4; ++i) {
        int g  = i * 512 + t;
        int wr = g >> 4, ch = g & 15;
        const float* src = W + wr * 128 + ch * 8;
        float4 f0 = *(const float4*)src;
        float4 f1 = *(const float4*)(src + 4);
        unsigned short u[8] = { f2bf(f0.x), f2bf(f0.y), f2bf(f0.z), f2bf(f0.w),
                                f2bf(f1.x), f2bf(f1.y), f2bf(f1.z), f2bf(f1.w) };
        int dst = wr * 128 + ((ch ^ (wr & 15)) << 3);
        *(uint4*)&Ws[dst] = *(const uint4*)u;
    }

    const int wid  = t >> 6;
    const int lane = t & 63;
    const int lr   = lane & 15;
    const int lk   = lane >> 4;
    const long base = (long)blockIdx.x * 128;

    long arow = base + wid * 16 + lr;
    bool rowok = arow < nrows;
    if (!rowok) arow = nrows - 1;

    // hoisted A-loads: 8 x float4 in flight
    float4 a[8];
    #pragma unroll
    for (int kc = 0; kc < 4; ++kc) {
        const float* ap = Xv + arow * 128 + kc * 32 + lk * 8;
        a[2 * kc]     = *(const float4*)ap;
        a[2 * kc + 1] = *(const float4*)(ap + 4);
    }
    __syncthreads();

    f32x4 acc[8] = {};
    #pragma unroll
    for (int kc = 0; kc < 4; ++kc) {
        bf16x8 af;
        af[0] = (short)f2bf(a[2*kc].x);   af[1] = (short)f2bf(a[2*kc].y);
        af[2] = (short)f2bf(a[2*kc].z);   af[3] = (short)f2bf(a[2*kc].w);
        af[4] = (short)f2bf(a[2*kc+1].x); af[5] = (short)f2bf(a[2*kc+1].y);
        af[6] = (short)f2bf(a[2*kc+1].z); af[7] = (short)f2bf(a[2*kc+1].w);
        #pragma unroll
        for (int jt = 0; jt < 8; ++jt) {
            int j  = jt * 16 + lr;
            int ch = (kc * 4 + lk) ^ lr;
            const bf16x8* bp = (const bf16x8*)&Ws[j * 128 + (ch << 3)];
            acc[jt] = __builtin_amdgcn_mfma_f32_16x16x32_bf16(*bp, af, acc[jt], 0, 0, 0);
        }
    }

    if (rowok) {
        unsigned short* yp = Y + arow * 128 + lk * 4;
        #pragma unroll
        for (int jt = 0; jt < 8; ++jt) {
            unsigned int d0 = (unsigned int)f2bf(acc[jt][0]) | ((unsigned int)f2bf(acc[jt][1]) << 16);
            unsigned int d1 = (unsigned int)f2bf(acc[jt][2]) | ((unsigned int)f2bf(acc[jt][3]) << 16);
            uint2 u; u.x = d0; u.y = d1;
            *(uint2*)(yp + jt * 16) = u;
        }
    }
}

// ---------------- shared helpers for aggregation ----------------
__device__ __forceinline__ void fma8(float* acc, float nm, uint4 q) {
    acc[0] += nm * bflo(q.x); acc[1] += nm * bfhi(q.x);
    acc[2] += nm * bflo(q.y); acc[3] += nm * bfhi(q.y);
    acc[4] += nm * bflo(q.z); acc[5] += nm * bfhi(q.z);
    acc[6] += nm * bflo(q.w); acc[7] += nm * bfhi(q.w);
}

// software-pipelined gather (depth-1, R13-proven)
__device__ __forceinline__ void agg_node(const int* __restrict__ rowptr,
                                         const int* __restrict__ srow,
                                         const float* __restrict__ dis,
                                         const unsigned short* __restrict__ xw,
                                         const float* __restrict__ b,
                                         long v, int c, float* o) {
    float dv = dis[v], s = dv * dv;
    float acc[8] = {};
    fma8(acc, s, *(const uint4*)(xw + v * 128 + c));   // self-loop

    int e0 = rowptr[v], e1 = rowptr[v + 1];
    int nfull = (e1 - e0) >> 2;
    int e = e0;
    if (nfull) {
        int r0 = srow[e], r1 = srow[e + 1], r2 = srow[e + 2], r3 = srow[e + 3];
        for (int bi = 1; bi < nfull; ++bi) {
            int eb = e0 + bi * 4;
            int p0 = srow[eb], p1 = srow[eb + 1], p2 = srow[eb + 2], p3 = srow[eb + 3];
            float n0 = dis[r0] * dv, n1 = dis[r1] * dv;
            float n2 = dis[r2] * dv, n3 = dis[r3] * dv;
            uint4 q0 = *(const uint4*)(xw + (long)r0 * 128 + c);
            uint4 q1 = *(const uint4*)(xw + (long)r1 * 128 + c);
            uint4 q2 = *(const uint4*)(xw + (long)r2 * 128 + c);
            uint4 q3 = *(const uint4*)(xw + (long)r3 * 128 + c);
            fma8(acc, n0, q0); fma8(acc, n1, q1);
            fma8(acc, n2, q2); fma8(acc, n3, q3);
            r0 = p0; r1 = p1; r2 = p2; r3 = p3;
        }
        float n0 = dis[r0] * dv, n1 = dis[r1] * dv;
        float n2 = dis[r2] * dv, n3 = dis[r3] * dv;
        uint4 q0 = *(const uint4*)(xw + (long)r0 * 128 + c);
        uint4 q1 = *(const uint4*)(xw + (long)r1 * 128 + c);
        uint4 q2 = *(const uint4*)(xw + (long)r2 * 128 + c);
        uint4 q3 = *(const uint4*)(xw + (long)r3 * 128 + c);
        fma8(acc, n0, q0); fma8(acc, n1, q1);
        fma8(acc, n2, q2); fma8(acc, n3, q3);
        e = e0 + nfull * 4;
    }
    for (; e < e1; ++e) {
        int   r1 = srow[e];
        float n1 = dis[r1] * dv;
        fma8(acc, n1, *(const uint4*)(xw + (long)r1 * 128 + c));
    }

    float4 b0 = *(const float4*)(b + c);
    float4 b1 = *(const float4*)(b + c + 4);
    o[0] = fmaxf(acc[0] + b0.x, 0.0f); o[1] = fmaxf(acc[1] + b0.y, 0.0f);
    o[2] = fmaxf(acc[2] + b0.z, 0.0f); o[3] = fmaxf(acc[3] + b0.w, 0.0f);
    o[4] = fmaxf(acc[4] + b1.x, 0.0f); o[5] = fmaxf(acc[5] + b1.y, 0.0f);
    o[6] = fmaxf(acc[6] + b1.z, 0.0f); o[7] = fmaxf(acc[7] + b1.w, 0.0f);
}

// ---------------- fused agg(layer1) + GEMM2, 64-row tiles (48 KB LDS -> 3 blocks/CU) ----------------
__global__ __launch_bounds__(512) void k_agg_gemm(const int* __restrict__ rowptr,
                                                  const int* __restrict__ srow,
                                                  const float* __restrict__ dis,
                                                  const unsigned short* __restrict__ xw,
                                                  const float* __restrict__ b1,
                                                  const float* __restrict__ W2,
                                                  unsigned short* __restrict__ Y,
                                                  int n) {
    __shared__ unsigned short Ws[128 * 128];   // W2, swizzled (32 KB)
    __shared__ unsigned short Hs[64 * 128];    // h1 tile, swizzled (16 KB)
    const int t = threadIdx.x;

    // stage W2 (no barrier needed until after agg phase)
    #pragma unroll
    for (int i = 0; i < 4; ++i) {
        int g  = i * 512 + t;
        int wr = g >> 4, ch = g & 15;
        const float* src = W2 + wr * 128 + ch * 8;
        float4 f0 = *(const float4*)src;
        float4 f1 = *(const float4*)(src + 4);
        unsigned short u[8] = { f2bf(f0.x), f2bf(f0.y), f2bf(f0.z), f2bf(f0.w),
                                f2bf(f1.x), f2bf(f1.y), f2bf(f1.z), f2bf(f1.w) };
        int dst = wr * 128 + ((ch ^ (wr & 15)) << 3);
        *(uint4*)&Ws[dst] = *(const uint4*)u;
    }

    // ---- agg phase: 2 passes x 32 nodes; write relu'd bf16 rows into Hs ----
    const long nb = (long)blockIdx.x * 64;
    const int c  = (t & 15) * 8;
    #pragma unroll
    for (int pass = 0; pass < 2; ++pass) {
        int  lrow = pass * 32 + (t >> 4);   // 0..63
        long v    = nb + lrow;
        float o[8] = {};
        if (v < n) agg_node(rowptr, srow, dis, xw, b1, v, c, o);
        unsigned int pk[4];
        pk[0] = (unsigned int)f2bf(o[0]) | ((unsigned int)f2bf(o[1]) << 16);
        pk[1] = (unsigned int)f2bf(o[2]) | ((unsigned int)f2bf(o[3]) << 16);
        pk[2] = (unsigned int)f2bf(o[4]) | ((unsigned int)f2bf(o[5]) << 16);
        pk[3] = (unsigned int)f2bf(o[6]) | ((unsigned int)f2bf(o[7]) << 16);
        int ch = (t & 15) ^ (lrow & 15);
        *(uint4*)&Hs[lrow * 128 + (ch << 3)] = *(const uint4*)pk;
    }
    __syncthreads();

    // ---- MFMA phase: wave w -> rows (w&3)*16..+15, jt in [(w>>2)*4, +4) ----
    const int wid  = t >> 6;
    const int lane = t & 63;
    const int lr   = lane & 15;
    const int lk   = lane >> 4;
    const int rw   = wid & 3;
    const int jb   = (wid >> 2) * 4;
    const int wrow = rw * 16 + lr;     // 0..63

    f32x4 acc[4] = {};
    #pragma unroll
    for (int kc = 0; kc < 4; ++kc) {
        int ach = (kc * 4 + lk) ^ (wrow & 15);
        bf16x8 af = *(const bf16x8*)&Hs[wrow * 128 + (ach << 3)];
        #pragma unroll
        for (int j4 = 0; j4 < 4; ++j4) {
            int j  = (jb + j4) * 16 + lr;
            int ch = (kc * 4 + lk) ^ lr;
            const bf16x8* bp = (const bf16x8*)&Ws[j * 128 + (ch << 3)];
            acc[j4] = __builtin_amdgcn_mfma_f32_16x16x32_bf16(*bp, af, acc[j4], 0, 0, 0);
        }
    }

    long grow = nb + wrow;
    if (grow < n) {
        unsigned short* yp = Y + grow * 128 + lk * 4;
        #pragma unroll
        for (int j4 = 0; j4 < 4; ++j4) {
            unsigned int d0 = (unsigned int)f2bf(acc[j4][0]) | ((unsigned int)f2bf(acc[j4][1]) << 16);
            unsigned int d1 = (unsigned int)f2bf(acc[j4][2]) | ((unsigned int)f2bf(acc[j4][3]) << 16);
            uint2 u; u.x = d0; u.y = d1;
            *(uint2*)(yp + (jb + j4) * 16) = u;
        }
    }
}

// ---------------- final aggregate: out(fp32) = relu(agg(xw2) + b2) ----------------
__global__ __launch_bounds__(256) void k_agg_out(const int* __restrict__ rowptr,
                                                 const int* __restrict__ srow,
                                                 const float* __restrict__ dis,
                                                 const unsigned short* __restrict__ xw,
                                                 const float* __restrict__ b,
                                                 float* __restrict__ out, int n) {
    long v = blockIdx.x * 16 + (threadIdx.x >> 4);
    if (v >= n) return;
    int c = (threadIdx.x & 15) * 8;
    float o[8];
    agg_node(rowptr, srow, dis, xw, b, v, c, o);
    float* op = out + v * 128 + c;
    *(float4*)op       = make_float4(o[0], o[1], o[2], o[3]);
    *(float4*)(op + 4) = make_float4(o[4], o[5], o[6], o[7]);
}

extern "C" void kernel_launch(void* const* d_in, const int* in_sizes, int n_in,
                              void* d_out, int out_size, void* d_ws, size_t ws_size,
                              hipStream_t stream) {
    const float* X  = (const float*)d_in[0];
    const float* W1 = (const float*)d_in[1];
    const float* b1 = (const float*)d_in[2];
    const float* W2 = (const float*)d_in[3];
    const float* b2 = (const float*)d_in[4];
    const int*   ei = (const int*)d_in[5];
    const int N = in_sizes[0] / DD;          // 100000
    const int E = in_sizes[5] / 2;           // 640000
    const int* row = ei;
    const int* col = ei + E;

    // -------- workspace carve-up --------
    char* p = (char*)d_ws;
    auto carve = [&](size_t bytes) { char* q = p; p += (bytes + 255) & ~(size_t)255; return q; };
    int*            cnt    = (int*)           carve((size_t)N * 4);
    int*            rowptr = (int*)           carve((size_t)(N + 1) * 4);
    int*            rank   = (int*)           carve((size_t)E * 4);
    int*            srow   = (int*)           carve((size_t)E * 4);
    float*          dis    = (float*)         carve((size_t)N * 4);
    unsigned short* xw     = (unsigned short*)carve((size_t)N * DD * 2);   // layer-1 XW
    unsigned short* xw2    = (unsigned short*)carve((size_t)N * DD * 2);   // layer-2 XW

    const int NBLK = (N + 255) / 256;        // 391
    const int gemm_grid = (N + 127) / 128;   // 782
    const int aggg_grid = (N + 63) / 64;     // 1563
    const int edge_grid = (E + 511) / 512;   // 1250
    const int aggo_grid = (N + 15) / 16;

    // -------- fused GEMM1 + edge count (+rank capture) --------
    hipMemsetAsync(cnt, 0, (size_t)N * 4, stream);
    k_gemm_mfma<<<gemm_grid + edge_grid, 512, 0, stream>>>(
        X, W1, xw, N, gemm_grid, col, cnt, rank, E);

    // -------- CSR build: single scan kernel, then atomic-free permute --------
    k_apply<<<NBLK, 256, 0, stream>>>(cnt, rowptr, dis, N);
    k_permute<<<(E + 255) / 256, 256, 0, stream>>>(row, col, rowptr, rank, srow, E);

    // -------- fused agg1 + GEMM2 (64-row tiles, 3 blocks/CU) --------
    k_agg_gemm<<<aggg_grid, 512, 0, stream>>>(rowptr, srow, dis, xw, b1, W2, xw2, N);

    // -------- final aggregate + bias + relu (fp32 out) --------
    k_agg_out<<<aggo_grid, 256, 0, stream>>>(rowptr, srow, dis, xw2, b2, (float*)d_out, N);
}

// Round 18
// 151.162 us; speedup vs baseline: 1.2991x; 1.2991x over previous
//
#include <hip/hip_runtime.h>

#define DD 128

typedef short bf16x8 __attribute__((ext_vector_type(8)));
typedef float f32x4 __attribute__((ext_vector_type(4)));

__device__ __forceinline__ unsigned short f2bf(float f) {   // fp32 -> bf16, RNE
    unsigned int u = __builtin_bit_cast(unsigned int, f);
    u += 0x7fffu + ((u >> 16) & 1u);
    return (unsigned short)(u >> 16);
}
__device__ __forceinline__ float bflo(unsigned int u) { return __builtin_bit_cast(float, u << 16); }
__device__ __forceinline__ float bfhi(unsigned int u) { return __builtin_bit_cast(float, u & 0xffff0000u); }

// ---------------- scan phase 1: per-block partial sums ----------------
__global__ __launch_bounds__(256) void k_part(const int* __restrict__ cnt,
                                              int* __restrict__ part, int n) {
    __shared__ int s[256];
    int t = threadIdx.x;
    int i = blockIdx.x * 256 + t;
    s[t] = (i < n) ? cnt[i] : 0;
    __syncthreads();
    for (int off = 128; off > 0; off >>= 1) {
        if (t < off) s[t] += s[t + off];
        __syncthreads();
    }
    if (t == 0) part[blockIdx.x] = s[0];
}

// ---------------- scan phase 2: per-block prefix over partials + local scan ----------------
__global__ __launch_bounds__(256) void k_apply(const int* __restrict__ cnt,
                                               const int* __restrict__ part,
                                               int* __restrict__ rowptr,
                                               float* __restrict__ dis, int n) {
    __shared__ int s[256];
    __shared__ int sbase;
    int t = threadIdx.x;
    int bid = blockIdx.x;

    int a = 0;
    for (int j = t; j < bid; j += 256) a += part[j];
    s[t] = a;
    __syncthreads();
    for (int off = 128; off > 0; off >>= 1) {
        if (t < off) s[t] += s[t + off];
        __syncthreads();
    }
    if (t == 0) sbase = s[0];
    __syncthreads();

    int i = bid * 256 + t;
    int c = (i < n) ? cnt[i] : 0;
    s[t] = c;
    __syncthreads();
    for (int off = 1; off < 256; off <<= 1) {
        int u = (t >= off) ? s[t - off] : 0;
        __syncthreads();
        s[t] += u;
        __syncthreads();
    }
    int base = sbase + s[t] - c;
    if (i < n) {
        rowptr[i] = base;
        dis[i] = rsqrtf((float)c + 1.0f);
        if (i == n - 1) rowptr[n] = base + c;
    }
}

// ---------------- permute: atomic-free (rank precomputed in count phase) ----------------
__global__ void k_permute(const int* __restrict__ row, const int* __restrict__ col,
                          const int* __restrict__ rowptr, const int* __restrict__ rank,
                          int* __restrict__ srow, int E) {
    int e = blockIdx.x * blockDim.x + threadIdx.x;
    if (e >= E) return;
    int p = rowptr[col[e]] + rank[e];
    srow[p] = row[e];
}

// ---------------- MFMA GEMM1: xw(bf16) = X(fp32) @ W1^T  (+ fused edge count + rank) ----------------
__global__ __launch_bounds__(512) void k_gemm_mfma(const float* __restrict__ Xv,
                                                   const float* __restrict__ W,
                                                   unsigned short* __restrict__ Y,
                                                   int nrows, int gemm_blocks,
                                                   const int* __restrict__ ecol,
                                                   int* __restrict__ cnt,
                                                   int* __restrict__ rank, int E) {
    __shared__ unsigned short Ws[128 * 128];   // 32 KB, 16B-chunk XOR swizzle
    const int t = threadIdx.x;

    if ((int)blockIdx.x >= gemm_blocks) {      // fused edge-count histogram + rank capture
        int e = (blockIdx.x - gemm_blocks) * 512 + t;
        if (e < E) {
            int r = atomicAdd(&cnt[ecol[e]], 1);
            rank[e] = r;                       // coalesced write
        }
        return;
    }

    #pragma unroll
    for (int i = 0; i < 4; ++i) {
        int g  = i * 512 + t;
        int wr = g >> 4, ch = g & 15;
        const float* src = W + wr * 128 + ch * 8;
        float4 f0 = *(const float4*)src;
        float4 f1 = *(const float4*)(src + 4);
        unsigned short u[8] = { f2bf(f0.x), f2bf(f0.y), f2bf(f0.z), f2bf(f0.w),
                                f2bf(f1.x), f2bf(f1.y), f2bf(f1.z), f2bf(f1.w) };
        int dst = wr * 128 + ((ch ^ (wr & 15)) << 3);
        *(uint4*)&Ws[dst] = *(const uint4*)u;
    }

    const int wid  = t >> 6;
    const int lane = t & 63;
    const int lr   = lane & 15;
    const int lk   = lane >> 4;
    const long base = (long)blockIdx.x * 128;

    long arow = base + wid * 16 + lr;
    bool rowok = arow < nrows;
    if (!rowok) arow = nrows - 1;

    // hoisted A-loads: 8 x float4 in flight
    float4 a[8];
    #pragma unroll
    for (int kc = 0; kc < 4; ++kc) {
        const float* ap = Xv + arow * 128 + kc * 32 + lk * 8;
        a[2 * kc]     = *(const float4*)ap;
        a[2 * kc + 1] = *(const float4*)(ap + 4);
    }
    __syncthreads();

    f32x4 acc[8] = {};
    #pragma unroll
    for (int kc = 0; kc < 4; ++kc) {
        bf16x8 af;
        af[0] = (short)f2bf(a[2*kc].x);   af[1] = (short)f2bf(a[2*kc].y);
        af[2] = (short)f2bf(a[2*kc].z);   af[3] = (short)f2bf(a[2*kc].w);
        af[4] = (short)f2bf(a[2*kc+1].x); af[5] = (short)f2bf(a[2*kc+1].y);
        af[6] = (short)f2bf(a[2*kc+1].z); af[7] = (short)f2bf(a[2*kc+1].w);
        #pragma unroll
        for (int jt = 0; jt < 8; ++jt) {
            int j  = jt * 16 + lr;
            int ch = (kc * 4 + lk) ^ lr;
            const bf16x8* bp = (const bf16x8*)&Ws[j * 128 + (ch << 3)];
            acc[jt] = __builtin_amdgcn_mfma_f32_16x16x32_bf16(*bp, af, acc[jt], 0, 0, 0);
        }
    }

    if (rowok) {
        unsigned short* yp = Y + arow * 128 + lk * 4;
        #pragma unroll
        for (int jt = 0; jt < 8; ++jt) {
            unsigned int d0 = (unsigned int)f2bf(acc[jt][0]) | ((unsigned int)f2bf(acc[jt][1]) << 16);
            unsigned int d1 = (unsigned int)f2bf(acc[jt][2]) | ((unsigned int)f2bf(acc[jt][3]) << 16);
            uint2 u; u.x = d0; u.y = d1;
            *(uint2*)(yp + jt * 16) = u;
        }
    }
}

// ---------------- shared helpers for aggregation ----------------
__device__ __forceinline__ void fma8(float* acc, float nm, uint4 q) {
    acc[0] += nm * bflo(q.x); acc[1] += nm * bfhi(q.x);
    acc[2] += nm * bflo(q.y); acc[3] += nm * bfhi(q.y);
    acc[4] += nm * bflo(q.z); acc[5] += nm * bfhi(q.z);
    acc[6] += nm * bflo(q.w); acc[7] += nm * bfhi(q.w);
}

// software-pipelined gather (depth-1, R13-proven)
__device__ __forceinline__ void agg_node(const int* __restrict__ rowptr,
                                         const int* __restrict__ srow,
                                         const float* __restrict__ dis,
                                         const unsigned short* __restrict__ xw,
                                         const float* __restrict__ b,
                                         long v, int c, float* o) {
    float dv = dis[v], s = dv * dv;
    float acc[8] = {};
    fma8(acc, s, *(const uint4*)(xw + v * 128 + c));   // self-loop

    int e0 = rowptr[v], e1 = rowptr[v + 1];
    int nfull = (e1 - e0) >> 2;
    int e = e0;
    if (nfull) {
        int r0 = srow[e], r1 = srow[e + 1], r2 = srow[e + 2], r3 = srow[e + 3];
        for (int bi = 1; bi < nfull; ++bi) {
            int eb = e0 + bi * 4;
            int p0 = srow[eb], p1 = srow[eb + 1], p2 = srow[eb + 2], p3 = srow[eb + 3];
            float n0 = dis[r0] * dv, n1 = dis[r1] * dv;
            float n2 = dis[r2] * dv, n3 = dis[r3] * dv;
            uint4 q0 = *(const uint4*)(xw + (long)r0 * 128 + c);
            uint4 q1 = *(const uint4*)(xw + (long)r1 * 128 + c);
            uint4 q2 = *(const uint4*)(xw + (long)r2 * 128 + c);
            uint4 q3 = *(const uint4*)(xw + (long)r3 * 128 + c);
            fma8(acc, n0, q0); fma8(acc, n1, q1);
            fma8(acc, n2, q2); fma8(acc, n3, q3);
            r0 = p0; r1 = p1; r2 = p2; r3 = p3;
        }
        float n0 = dis[r0] * dv, n1 = dis[r1] * dv;
        float n2 = dis[r2] * dv, n3 = dis[r3] * dv;
        uint4 q0 = *(const uint4*)(xw + (long)r0 * 128 + c);
        uint4 q1 = *(const uint4*)(xw + (long)r1 * 128 + c);
        uint4 q2 = *(const uint4*)(xw + (long)r2 * 128 + c);
        uint4 q3 = *(const uint4*)(xw + (long)r3 * 128 + c);
        fma8(acc, n0, q0); fma8(acc, n1, q1);
        fma8(acc, n2, q2); fma8(acc, n3, q3);
        e = e0 + nfull * 4;
    }
    for (; e < e1; ++e) {
        int   r1 = srow[e];
        float n1 = dis[r1] * dv;
        fma8(acc, n1, *(const uint4*)(xw + (long)r1 * 128 + c));
    }

    float4 b0 = *(const float4*)(b + c);
    float4 b1 = *(const float4*)(b + c + 4);
    o[0] = fmaxf(acc[0] + b0.x, 0.0f); o[1] = fmaxf(acc[1] + b0.y, 0.0f);
    o[2] = fmaxf(acc[2] + b0.z, 0.0f); o[3] = fmaxf(acc[3] + b0.w, 0.0f);
    o[4] = fmaxf(acc[4] + b1.x, 0.0f); o[5] = fmaxf(acc[5] + b1.y, 0.0f);
    o[6] = fmaxf(acc[6] + b1.z, 0.0f); o[7] = fmaxf(acc[7] + b1.w, 0.0f);
}

// ---------------- fused agg(layer1) + GEMM2, 64-row tiles (48 KB LDS -> 3 blocks/CU) ----------------
__global__ __launch_bounds__(512) void k_agg_gemm(const int* __restrict__ rowptr,
                                                  const int* __restrict__ srow,
                                                  const float* __restrict__ dis,
                                                  const unsigned short* __restrict__ xw,
                                                  const float* __restrict__ b1,
                                                  const float* __restrict__ W2,
                                                  unsigned short* __restrict__ Y,
                                                  int n) {
    __shared__ unsigned short Ws[128 * 128];   // W2, swizzled (32 KB)
    __shared__ unsigned short Hs[64 * 128];    // h1 tile, swizzled (16 KB)
    const int t = threadIdx.x;

    // stage W2 (no barrier needed until after agg phase)
    #pragma unroll
    for (int i = 0; i < 4; ++i) {
        int g  = i * 512 + t;
        int wr = g >> 4, ch = g & 15;
        const float* src = W2 + wr * 128 + ch * 8;
        float4 f0 = *(const float4*)src;
        float4 f1 = *(const float4*)(src + 4);
        unsigned short u[8] = { f2bf(f0.x), f2bf(f0.y), f2bf(f0.z), f2bf(f0.w),
                                f2bf(f1.x), f2bf(f1.y), f2bf(f1.z), f2bf(f1.w) };
        int dst = wr * 128 + ((ch ^ (wr & 15)) << 3);
        *(uint4*)&Ws[dst] = *(const uint4*)u;
    }

    // ---- agg phase: 2 passes x 32 nodes; write relu'd bf16 rows into Hs ----
    const long nb = (long)blockIdx.x * 64;
    const int c  = (t & 15) * 8;
    #pragma unroll
    for (int pass = 0; pass < 2; ++pass) {
        int  lrow = pass * 32 + (t >> 4);   // 0..63
        long v    = nb + lrow;
        float o[8] = {};
        if (v < n) agg_node(rowptr, srow, dis, xw, b1, v, c, o);
        unsigned int pk[4];
        pk[0] = (unsigned int)f2bf(o[0]) | ((unsigned int)f2bf(o[1]) << 16);
        pk[1] = (unsigned int)f2bf(o[2]) | ((unsigned int)f2bf(o[3]) << 16);
        pk[2] = (unsigned int)f2bf(o[4]) | ((unsigned int)f2bf(o[5]) << 16);
        pk[3] = (unsigned int)f2bf(o[6]) | ((unsigned int)f2bf(o[7]) << 16);
        int ch = (t & 15) ^ (lrow & 15);
        *(uint4*)&Hs[lrow * 128 + (ch << 3)] = *(const uint4*)pk;
    }
    __syncthreads();

    // ---- MFMA phase: wave w -> rows (w&3)*16..+15, jt in [(w>>2)*4, +4) ----
    const int wid  = t >> 6;
    const int lane = t & 63;
    const int lr   = lane & 15;
    const int lk   = lane >> 4;
    const int rw   = wid & 3;
    const int jb   = (wid >> 2) * 4;
    const int wrow = rw * 16 + lr;     // 0..63

    f32x4 acc[4] = {};
    #pragma unroll
    for (int kc = 0; kc < 4; ++kc) {
        int ach = (kc * 4 + lk) ^ (wrow & 15);
        bf16x8 af = *(const bf16x8*)&Hs[wrow * 128 + (ach << 3)];
        #pragma unroll
        for (int j4 = 0; j4 < 4; ++j4) {
            int j  = (jb + j4) * 16 + lr;
            int ch = (kc * 4 + lk) ^ lr;
            const bf16x8* bp = (const bf16x8*)&Ws[j * 128 + (ch << 3)];
            acc[j4] = __builtin_amdgcn_mfma_f32_16x16x32_bf16(*bp, af, acc[j4], 0, 0, 0);
        }
    }

    long grow = nb + wrow;
    if (grow < n) {
        unsigned short* yp = Y + grow * 128 + lk * 4;
        #pragma unroll
        for (int j4 = 0; j4 < 4; ++j4) {
            unsigned int d0 = (unsigned int)f2bf(acc[j4][0]) | ((unsigned int)f2bf(acc[j4][1]) << 16);
            unsigned int d1 = (unsigned int)f2bf(acc[j4][2]) | ((unsigned int)f2bf(acc[j4][3]) << 16);
            uint2 u; u.x = d0; u.y = d1;
            *(uint2*)(yp + (jb + j4) * 16) = u;
        }
    }
}

// ---------------- final aggregate: out(fp32) = relu(agg(xw2) + b2) ----------------
__global__ __launch_bounds__(256) void k_agg_out(const int* __restrict__ rowptr,
                                                 const int* __restrict__ srow,
                                                 const float* __restrict__ dis,
                                                 const unsigned short* __restrict__ xw,
                                                 const float* __restrict__ b,
                                                 float* __restrict__ out, int n) {
    long v = blockIdx.x * 16 + (threadIdx.x >> 4);
    if (v >= n) return;
    int c = (threadIdx.x & 15) * 8;
    float o[8];
    agg_node(rowptr, srow, dis, xw, b, v, c, o);
    float* op = out + v * 128 + c;
    *(float4*)op       = make_float4(o[0], o[1], o[2], o[3]);
    *(float4*)(op + 4) = make_float4(o[4], o[5], o[6], o[7]);
}

extern "C" void kernel_launch(void* const* d_in, const int* in_sizes, int n_in,
                              void* d_out, int out_size, void* d_ws, size_t ws_size,
                              hipStream_t stream) {
    const float* X  = (const float*)d_in[0];
    const float* W1 = (const float*)d_in[1];
    const float* b1 = (const float*)d_in[2];
    const float* W2 = (const float*)d_in[3];
    const float* b2 = (const float*)d_in[4];
    const int*   ei = (const int*)d_in[5];
    const int N = in_sizes[0] / DD;          // 100000
    const int E = in_sizes[5] / 2;           // 640000
    const int* row = ei;
    const int* col = ei + E;

    // -------- workspace carve-up --------
    char* p = (char*)d_ws;
    auto carve = [&](size_t bytes) { char* q = p; p += (bytes + 255) & ~(size_t)255; return q; };
    int*            cnt    = (int*)           carve((size_t)N * 4);
    int*            rowptr = (int*)           carve((size_t)(N + 1) * 4);
    int*            part   = (int*)           carve(1024 * 4);
    int*            rank   = (int*)           carve((size_t)E * 4);
    int*            srow   = (int*)           carve((size_t)E * 4);
    float*          dis    = (float*)         carve((size_t)N * 4);
    unsigned short* xw     = (unsigned short*)carve((size_t)N * DD * 2);   // layer-1 XW
    unsigned short* xw2    = (unsigned short*)carve((size_t)N * DD * 2);   // layer-2 XW

    const int NBLK = (N + 255) / 256;        // 391
    const int gemm_grid = (N + 127) / 128;   // 782
    const int aggg_grid = (N + 63) / 64;     // 1563
    const int edge_grid = (E + 511) / 512;   // 1250
    const int aggo_grid = (N + 15) / 16;

    // -------- fused GEMM1 + edge count (+rank capture) --------
    hipMemsetAsync(cnt, 0, (size_t)N * 4, stream);
    k_gemm_mfma<<<gemm_grid + edge_grid, 512, 0, stream>>>(
        X, W1, xw, N, gemm_grid, col, cnt, rank, E);

    // -------- CSR build: two-phase scan (R16-proven) + atomic-free permute --------
    k_part<<<NBLK, 256, 0, stream>>>(cnt, part, N);
    k_apply<<<NBLK, 256, 0, stream>>>(cnt, part, rowptr, dis, N);
    k_permute<<<(E + 255) / 256, 256, 0, stream>>>(row, col, rowptr, rank, srow, E);

    // -------- fused agg1 + GEMM2 (64-row tiles, 3 blocks/CU) --------
    k_agg_gemm<<<aggg_grid, 512, 0, stream>>>(rowptr, srow, dis, xw, b1, W2, xw2, N);

    // -------- final aggregate + bias + relu (fp32 out) --------
    k_agg_out<<<aggo_grid, 256, 0, stream>>>(rowptr, srow, dis, xw2, b2, (float*)d_out, N);
}

// Round 19
// 147.979 us; speedup vs baseline: 1.3270x; 1.0215x over previous
//
#include <hip/hip_runtime.h>

#define DD 128

typedef short bf16x8 __attribute__((ext_vector_type(8)));
typedef float f32x4 __attribute__((ext_vector_type(4)));

__device__ __forceinline__ unsigned short f2bf(float f) {   // fp32 -> bf16, RNE
    unsigned int u = __builtin_bit_cast(unsigned int, f);
    u += 0x7fffu + ((u >> 16) & 1u);
    return (unsigned short)(u >> 16);
}
__device__ __forceinline__ float bflo(unsigned int u) { return __builtin_bit_cast(float, u << 16); }
__device__ __forceinline__ float bfhi(unsigned int u) { return __builtin_bit_cast(float, u & 0xffff0000u); }

// ---------------- scan phase 1: per-block partial sums ----------------
__global__ __launch_bounds__(256) void k_part(const int* __restrict__ cnt,
                                              int* __restrict__ part, int n) {
    __shared__ int s[256];
    int t = threadIdx.x;
    int i = blockIdx.x * 256 + t;
    s[t] = (i < n) ? cnt[i] : 0;
    __syncthreads();
    for (int off = 128; off > 0; off >>= 1) {
        if (t < off) s[t] += s[t + off];
        __syncthreads();
    }
    if (t == 0) part[blockIdx.x] = s[0];
}

// ---------------- scan phase 2: per-block prefix over partials + local scan ----------------
__global__ __launch_bounds__(256) void k_apply(const int* __restrict__ cnt,
                                               const int* __restrict__ part,
                                               int* __restrict__ rowptr,
                                               float* __restrict__ dis, int n) {
    __shared__ int s[256];
    __shared__ int sbase;
    int t = threadIdx.x;
    int bid = blockIdx.x;

    int a = 0;
    for (int j = t; j < bid; j += 256) a += part[j];
    s[t] = a;
    __syncthreads();
    for (int off = 128; off > 0; off >>= 1) {
        if (t < off) s[t] += s[t + off];
        __syncthreads();
    }
    if (t == 0) sbase = s[0];
    __syncthreads();

    int i = bid * 256 + t;
    int c = (i < n) ? cnt[i] : 0;
    s[t] = c;
    __syncthreads();
    for (int off = 1; off < 256; off <<= 1) {
        int u = (t >= off) ? s[t - off] : 0;
        __syncthreads();
        s[t] += u;
        __syncthreads();
    }
    int base = sbase + s[t] - c;
    if (i < n) {
        rowptr[i] = base;
        dis[i] = rsqrtf((float)c + 1.0f);
        if (i == n - 1) rowptr[n] = base + c;
    }
}

// ---------------- permute: atomic-free (rank precomputed in count phase) ----------------
__global__ void k_permute(const int* __restrict__ row, const int* __restrict__ col,
                          const int* __restrict__ rowptr, const int* __restrict__ rank,
                          int* __restrict__ srow, int E) {
    int e = blockIdx.x * blockDim.x + threadIdx.x;
    if (e >= E) return;
    int p = rowptr[col[e]] + rank[e];
    srow[p] = row[e];
}

// ---------------- MFMA GEMM1: xw(bf16) = X(fp32) @ W1^T  (+ fused edge count + rank) ----------------
__global__ __launch_bounds__(512) void k_gemm_mfma(const float* __restrict__ Xv,
                                                   const float* __restrict__ W,
                                                   unsigned short* __restrict__ Y,
                                                   int nrows, int gemm_blocks,
                                                   const int* __restrict__ ecol,
                                                   int* __restrict__ cnt,
                                                   int* __restrict__ rank, int E) {
    __shared__ unsigned short Ws[128 * 128];   // 32 KB, 16B-chunk XOR swizzle
    const int t = threadIdx.x;

    if ((int)blockIdx.x >= gemm_blocks) {      // fused edge-count histogram + rank capture
        int e = (blockIdx.x - gemm_blocks) * 512 + t;
        if (e < E) {
            int r = atomicAdd(&cnt[ecol[e]], 1);
            rank[e] = r;                       // coalesced write
        }
        return;
    }

    #pragma unroll
    for (int i = 0; i < 4; ++i) {
        int g  = i * 512 + t;
        int wr = g >> 4, ch = g & 15;
        const float* src = W + wr * 128 + ch * 8;
        float4 f0 = *(const float4*)src;
        float4 f1 = *(const float4*)(src + 4);
        unsigned short u[8] = { f2bf(f0.x), f2bf(f0.y), f2bf(f0.z), f2bf(f0.w),
                                f2bf(f1.x), f2bf(f1.y), f2bf(f1.z), f2bf(f1.w) };
        int dst = wr * 128 + ((ch ^ (wr & 15)) << 3);
        *(uint4*)&Ws[dst] = *(const uint4*)u;
    }

    const int wid  = t >> 6;
    const int lane = t & 63;
    const int lr   = lane & 15;
    const int lk   = lane >> 4;
    const long base = (long)blockIdx.x * 128;

    long arow = base + wid * 16 + lr;
    bool rowok = arow < nrows;
    if (!rowok) arow = nrows - 1;

    // hoisted A-loads: 8 x float4 in flight
    float4 a[8];
    #pragma unroll
    for (int kc = 0; kc < 4; ++kc) {
        const float* ap = Xv + arow * 128 + kc * 32 + lk * 8;
        a[2 * kc]     = *(const float4*)ap;
        a[2 * kc + 1] = *(const float4*)(ap + 4);
    }
    __syncthreads();

    f32x4 acc[8] = {};
    #pragma unroll
    for (int kc = 0; kc < 4; ++kc) {
        bf16x8 af;
        af[0] = (short)f2bf(a[2*kc].x);   af[1] = (short)f2bf(a[2*kc].y);
        af[2] = (short)f2bf(a[2*kc].z);   af[3] = (short)f2bf(a[2*kc].w);
        af[4] = (short)f2bf(a[2*kc+1].x); af[5] = (short)f2bf(a[2*kc+1].y);
        af[6] = (short)f2bf(a[2*kc+1].z); af[7] = (short)f2bf(a[2*kc+1].w);
        #pragma unroll
        for (int jt = 0; jt < 8; ++jt) {
            int j  = jt * 16 + lr;
            int ch = (kc * 4 + lk) ^ lr;
            const bf16x8* bp = (const bf16x8*)&Ws[j * 128 + (ch << 3)];
            acc[jt] = __builtin_amdgcn_mfma_f32_16x16x32_bf16(*bp, af, acc[jt], 0, 0, 0);
        }
    }

    if (rowok) {
        unsigned short* yp = Y + arow * 128 + lk * 4;
        #pragma unroll
        for (int jt = 0; jt < 8; ++jt) {
            unsigned int d0 = (unsigned int)f2bf(acc[jt][0]) | ((unsigned int)f2bf(acc[jt][1]) << 16);
            unsigned int d1 = (unsigned int)f2bf(acc[jt][2]) | ((unsigned int)f2bf(acc[jt][3]) << 16);
            uint2 u; u.x = d0; u.y = d1;
            *(uint2*)(yp + jt * 16) = u;
        }
    }
}

// ---------------- shared helpers for aggregation ----------------
__device__ __forceinline__ void fma8(float* acc, float nm, uint4 q) {
    acc[0] += nm * bflo(q.x); acc[1] += nm * bfhi(q.x);
    acc[2] += nm * bflo(q.y); acc[3] += nm * bfhi(q.y);
    acc[4] += nm * bflo(q.z); acc[5] += nm * bfhi(q.z);
    acc[6] += nm * bflo(q.w); acc[7] += nm * bfhi(q.w);
}

// software-pipelined gather (depth-1, R13-proven)
__device__ __forceinline__ void agg_node(const int* __restrict__ rowptr,
                                         const int* __restrict__ srow,
                                         const float* __restrict__ dis,
                                         const unsigned short* __restrict__ xw,
                                         const float* __restrict__ b,
                                         long v, int c, float* o) {
    float dv = dis[v], s = dv * dv;
    float acc[8] = {};
    fma8(acc, s, *(const uint4*)(xw + v * 128 + c));   // self-loop

    int e0 = rowptr[v], e1 = rowptr[v + 1];
    int nfull = (e1 - e0) >> 2;
    int e = e0;
    if (nfull) {
        int r0 = srow[e], r1 = srow[e + 1], r2 = srow[e + 2], r3 = srow[e + 3];
        for (int bi = 1; bi < nfull; ++bi) {
            int eb = e0 + bi * 4;
            int p0 = srow[eb], p1 = srow[eb + 1], p2 = srow[eb + 2], p3 = srow[eb + 3];
            float n0 = dis[r0] * dv, n1 = dis[r1] * dv;
            float n2 = dis[r2] * dv, n3 = dis[r3] * dv;
            uint4 q0 = *(const uint4*)(xw + (long)r0 * 128 + c);
            uint4 q1 = *(const uint4*)(xw + (long)r1 * 128 + c);
            uint4 q2 = *(const uint4*)(xw + (long)r2 * 128 + c);
            uint4 q3 = *(const uint4*)(xw + (long)r3 * 128 + c);
            fma8(acc, n0, q0); fma8(acc, n1, q1);
            fma8(acc, n2, q2); fma8(acc, n3, q3);
            r0 = p0; r1 = p1; r2 = p2; r3 = p3;
        }
        float n0 = dis[r0] * dv, n1 = dis[r1] * dv;
        float n2 = dis[r2] * dv, n3 = dis[r3] * dv;
        uint4 q0 = *(const uint4*)(xw + (long)r0 * 128 + c);
        uint4 q1 = *(const uint4*)(xw + (long)r1 * 128 + c);
        uint4 q2 = *(const uint4*)(xw + (long)r2 * 128 + c);
        uint4 q3 = *(const uint4*)(xw + (long)r3 * 128 + c);
        fma8(acc, n0, q0); fma8(acc, n1, q1);
        fma8(acc, n2, q2); fma8(acc, n3, q3);
        e = e0 + nfull * 4;
    }
    for (; e < e1; ++e) {
        int   r1 = srow[e];
        float n1 = dis[r1] * dv;
        fma8(acc, n1, *(const uint4*)(xw + (long)r1 * 128 + c));
    }

    float4 b0 = *(const float4*)(b + c);
    float4 b1 = *(const float4*)(b + c + 4);
    o[0] = fmaxf(acc[0] + b0.x, 0.0f); o[1] = fmaxf(acc[1] + b0.y, 0.0f);
    o[2] = fmaxf(acc[2] + b0.z, 0.0f); o[3] = fmaxf(acc[3] + b0.w, 0.0f);
    o[4] = fmaxf(acc[4] + b1.x, 0.0f); o[5] = fmaxf(acc[5] + b1.y, 0.0f);
    o[6] = fmaxf(acc[6] + b1.z, 0.0f); o[7] = fmaxf(acc[7] + b1.w, 0.0f);
}

// ---------------- fused agg(layer1) + GEMM2, 32-row tiles ----------------
// LDS = Ws 32 KB + Hs 8 KB = 40 KB -> 4 blocks/CU (2048 threads, 100% cap).
// agg: 1 pass x 32 nodes. MFMA: 8 waves = 2 row-groups x 4 jt-pairs, acc[2].
__global__ __launch_bounds__(512) void k_agg_gemm(const int* __restrict__ rowptr,
                                                  const int* __restrict__ srow,
                                                  const float* __restrict__ dis,
                                                  const unsigned short* __restrict__ xw,
                                                  const float* __restrict__ b1,
                                                  const float* __restrict__ W2,
                                                  unsigned short* __restrict__ Y,
                                                  int n) {
    __shared__ unsigned short Ws[128 * 128];   // W2, swizzled (32 KB)
    __shared__ unsigned short Hs[32 * 128];    // h1 tile, swizzled (8 KB)
    const int t = threadIdx.x;

    // stage W2 (no barrier needed until after agg phase)
    #pragma unroll
    for (int i = 0; i < 4; ++i) {
        int g  = i * 512 + t;
        int wr = g >> 4, ch = g & 15;
        const float* src = W2 + wr * 128 + ch * 8;
        float4 f0 = *(const float4*)src;
        float4 f1 = *(const float4*)(src + 4);
        unsigned short u[8] = { f2bf(f0.x), f2bf(f0.y), f2bf(f0.z), f2bf(f0.w),
                                f2bf(f1.x), f2bf(f1.y), f2bf(f1.z), f2bf(f1.w) };
        int dst = wr * 128 + ((ch ^ (wr & 15)) << 3);
        *(uint4*)&Ws[dst] = *(const uint4*)u;
    }

    // ---- agg phase: 1 pass x 32 nodes; write relu'd bf16 rows into Hs ----
    const long nb = (long)blockIdx.x * 32;
    const int c    = (t & 15) * 8;
    const int lrow = t >> 4;               // 0..31
    {
        long v = nb + lrow;
        float o[8] = {};
        if (v < n) agg_node(rowptr, srow, dis, xw, b1, v, c, o);
        unsigned int pk[4];
        pk[0] = (unsigned int)f2bf(o[0]) | ((unsigned int)f2bf(o[1]) << 16);
        pk[1] = (unsigned int)f2bf(o[2]) | ((unsigned int)f2bf(o[3]) << 16);
        pk[2] = (unsigned int)f2bf(o[4]) | ((unsigned int)f2bf(o[5]) << 16);
        pk[3] = (unsigned int)f2bf(o[6]) | ((unsigned int)f2bf(o[7]) << 16);
        int ch = (t & 15) ^ (lrow & 15);
        *(uint4*)&Hs[lrow * 128 + (ch << 3)] = *(const uint4*)pk;
    }
    __syncthreads();

    // ---- MFMA phase: wave w -> rows (w&1)*16..+15, jt in {(w>>1)*2, +1} ----
    const int wid  = t >> 6;
    const int lane = t & 63;
    const int lr   = lane & 15;
    const int lk   = lane >> 4;
    const int rw   = wid & 1;
    const int jb   = (wid >> 1) * 2;
    const int wrow = rw * 16 + lr;     // 0..31

    f32x4 acc[2] = {};
    #pragma unroll
    for (int kc = 0; kc < 4; ++kc) {
        int ach = (kc * 4 + lk) ^ (wrow & 15);
        bf16x8 af = *(const bf16x8*)&Hs[wrow * 128 + (ach << 3)];
        #pragma unroll
        for (int j2 = 0; j2 < 2; ++j2) {
            int j  = (jb + j2) * 16 + lr;
            int ch = (kc * 4 + lk) ^ lr;
            const bf16x8* bp = (const bf16x8*)&Ws[j * 128 + (ch << 3)];
            acc[j2] = __builtin_amdgcn_mfma_f32_16x16x32_bf16(*bp, af, acc[j2], 0, 0, 0);
        }
    }

    long grow = nb + wrow;
    if (grow < n) {
        unsigned short* yp = Y + grow * 128 + lk * 4;
        #pragma unroll
        for (int j2 = 0; j2 < 2; ++j2) {
            unsigned int d0 = (unsigned int)f2bf(acc[j2][0]) | ((unsigned int)f2bf(acc[j2][1]) << 16);
            unsigned int d1 = (unsigned int)f2bf(acc[j2][2]) | ((unsigned int)f2bf(acc[j2][3]) << 16);
            uint2 u; u.x = d0; u.y = d1;
            *(uint2*)(yp + (jb + j2) * 16) = u;
        }
    }
}

// ---------------- final aggregate: out(fp32) = relu(agg(xw2) + b2) ----------------
__global__ __launch_bounds__(256) void k_agg_out(const int* __restrict__ rowptr,
                                                 const int* __restrict__ srow,
                                                 const float* __restrict__ dis,
                                                 const unsigned short* __restrict__ xw,
                                                 const float* __restrict__ b,
                                                 float* __restrict__ out, int n) {
    long v = blockIdx.x * 16 + (threadIdx.x >> 4);
    if (v >= n) return;
    int c = (threadIdx.x & 15) * 8;
    float o[8];
    agg_node(rowptr, srow, dis, xw, b, v, c, o);
    float* op = out + v * 128 + c;
    *(float4*)op       = make_float4(o[0], o[1], o[2], o[3]);
    *(float4*)(op + 4) = make_float4(o[4], o[5], o[6], o[7]);
}

extern "C" void kernel_launch(void* const* d_in, const int* in_sizes, int n_in,
                              void* d_out, int out_size, void* d_ws, size_t ws_size,
                              hipStream_t stream) {
    const float* X  = (const float*)d_in[0];
    const float* W1 = (const float*)d_in[1];
    const float* b1 = (const float*)d_in[2];
    const float* W2 = (const float*)d_in[3];
    const float* b2 = (const float*)d_in[4];
    const int*   ei = (const int*)d_in[5];
    const int N = in_sizes[0] / DD;          // 100000
    const int E = in_sizes[5] / 2;           // 640000
    const int* row = ei;
    const int* col = ei + E;

    // -------- workspace carve-up --------
    char* p = (char*)d_ws;
    auto carve = [&](size_t bytes) { char* q = p; p += (bytes + 255) & ~(size_t)255; return q; };
    int*            cnt    = (int*)           carve((size_t)N * 4);
    int*            rowptr = (int*)           carve((size_t)(N + 1) * 4);
    int*            part   = (int*)           carve(1024 * 4);
    int*            rank   = (int*)           carve((size_t)E * 4);
    int*            srow   = (int*)           carve((size_t)E * 4);
    float*          dis    = (float*)         carve((size_t)N * 4);
    unsigned short* xw     = (unsigned short*)carve((size_t)N * DD * 2);   // layer-1 XW
    unsigned short* xw2    = (unsigned short*)carve((size_t)N * DD * 2);   // layer-2 XW

    const int NBLK = (N + 255) / 256;        // 391
    const int gemm_grid = (N + 127) / 128;   // 782
    const int aggg_grid = (N + 31) / 32;     // 3125
    const int edge_grid = (E + 511) / 512;   // 1250
    const int aggo_grid = (N + 15) / 16;

    // -------- fused GEMM1 + edge count (+rank capture) --------
    hipMemsetAsync(cnt, 0, (size_t)N * 4, stream);
    k_gemm_mfma<<<gemm_grid + edge_grid, 512, 0, stream>>>(
        X, W1, xw, N, gemm_grid, col, cnt, rank, E);

    // -------- CSR build: two-phase scan + atomic-free permute --------
    k_part<<<NBLK, 256, 0, stream>>>(cnt, part, N);
    k_apply<<<NBLK, 256, 0, stream>>>(cnt, part, rowptr, dis, N);
    k_permute<<<(E + 255) / 256, 256, 0, stream>>>(row, col, rowptr, rank, srow, E);

    // -------- fused agg1 + GEMM2 (32-row tiles, 4 blocks/CU) --------
    k_agg_gemm<<<aggg_grid, 512, 0, stream>>>(rowptr, srow, dis, xw, b1, W2, xw2, N);

    // -------- final aggregate + bias + relu (fp32 out) --------
    k_agg_out<<<aggo_grid, 256, 0, stream>>>(rowptr, srow, dis, xw2, b2, (float*)d_out, N);
}